// Round 1
// baseline (468.375 us; speedup 1.0000x reference)
//
#include <hip/hip_runtime.h>

#define NN 50000
#define EE 800000
#define IND 256
#define HD 128

// ---------------- fc1: h = relu(x @ W1 + b1) ----------------
// block = 128 threads (one per output col), 16 rows per block.
__global__ __launch_bounds__(128) void fc1_kernel(const float* __restrict__ x,
                                                  const float* __restrict__ W1,
                                                  const float* __restrict__ b1,
                                                  float* __restrict__ h) {
  __shared__ float xs[16][IND];
  const int col = threadIdx.x;
  const int row0 = blockIdx.x * 16;
  // cooperative load of 16x256 floats = 1024 float4, 8 per thread, coalesced
  const float4* xsrc = (const float4*)(x + (size_t)row0 * IND);
  float4* xdst = (float4*)(&xs[0][0]);
#pragma unroll
  for (int i = 0; i < 8; ++i) xdst[col + i * 128] = xsrc[col + i * 128];
  __syncthreads();

  float acc[16];
#pragma unroll
  for (int r = 0; r < 16; ++r) acc[r] = 0.f;

  for (int k = 0; k < IND; k += 4) {
    const float w0 = W1[(k + 0) * HD + col];
    const float w1 = W1[(k + 1) * HD + col];
    const float w2 = W1[(k + 2) * HD + col];
    const float w3 = W1[(k + 3) * HD + col];
#pragma unroll
    for (int r = 0; r < 16; ++r) {
      float4 xv = *(const float4*)&xs[r][k];
      acc[r] = fmaf(xv.x, w0, acc[r]);
      acc[r] = fmaf(xv.y, w1, acc[r]);
      acc[r] = fmaf(xv.z, w2, acc[r]);
      acc[r] = fmaf(xv.w, w3, acc[r]);
    }
  }
  const float bb = b1[col];
#pragma unroll
  for (int r = 0; r < 16; ++r)
    h[(size_t)(row0 + r) * HD + col] = fmaxf(acc[r] + bb, 0.f);
}

// ---------------- CSR build ----------------
__global__ void hist_kernel(const int* __restrict__ rows, int* __restrict__ counts) {
  int e = blockIdx.x * 256 + threadIdx.x;
  if (e < EE) atomicAdd(&counts[rows[e]], 1);
}

__device__ inline int wave_incl_scan(int v, int lane) {
#pragma unroll
  for (int off = 1; off < 64; off <<= 1) {
    int n = __shfl_up(v, off);
    if (lane >= off) v += n;
  }
  return v;
}

// single-block hierarchical scan: row_ptr (exclusive, shifted) + cursor copy
__global__ __launch_bounds__(1024) void scan_kernel(const int* __restrict__ counts,
                                                    int* __restrict__ row_ptr,
                                                    int* __restrict__ cursor) {
  __shared__ int wsum[16];
  __shared__ int carry_s;
  const int t = threadIdx.x;
  const int lane = t & 63;
  const int wid = t >> 6;
  if (t == 0) { carry_s = 0; row_ptr[0] = 0; }
  __syncthreads();
  for (int base = 0; base < NN; base += 1024) {
    const int i = base + t;
    const int v = (i < NN) ? counts[i] : 0;
    int sc = wave_incl_scan(v, lane);
    if (lane == 63) wsum[wid] = sc;
    __syncthreads();
    if (wid == 0) {
      int ws = (lane < 16) ? wsum[lane] : 0;
      int wsc = wave_incl_scan(ws, lane);
      if (lane < 16) wsum[lane] = wsc - ws;  // exclusive wave offsets
    }
    __syncthreads();
    const int incl = sc + wsum[wid];
    const int carry = carry_s;
    if (i < NN) {
      row_ptr[i + 1] = carry + incl;
      cursor[i] = carry + incl - v;  // exclusive start for permute
    }
    __syncthreads();
    if (t == 1023) carry_s = carry + incl;
    __syncthreads();
  }
}

// scatter edges into row-sorted arrays (materialize sorted val/col)
__global__ void permute_kernel(const int* __restrict__ rows, const int* __restrict__ cols,
                               const float* __restrict__ vals, int* __restrict__ cursor,
                               float* __restrict__ vals_s, int* __restrict__ cols_s) {
  int e = blockIdx.x * 256 + threadIdx.x;
  if (e < EE) {
    int r = rows[e];
    int pos = atomicAdd(&cursor[r], 1);
    vals_s[pos] = vals[e];
    cols_s[pos] = cols[e];
  }
}

// ---------------- SpMM: agg[i] = sum_{e: row=i} val_e * h[col_e] ----------------
// one block (128 threads = dims) per node; no atomics.
__global__ __launch_bounds__(128) void spmm_kernel(const float* __restrict__ h,
                                                   const float* __restrict__ vals_s,
                                                   const int* __restrict__ cols_s,
                                                   const int* __restrict__ row_ptr,
                                                   float* __restrict__ agg) {
  const int i = blockIdx.x;
  const int d = threadIdx.x;
  const int s = row_ptr[i];
  const int e = row_ptr[i + 1];
  float acc = 0.f;
  for (int t = s; t < e; ++t) {
    const float v = vals_s[t];
    const int c = cols_s[t];
    acc = fmaf(v, h[(size_t)c * HD + d], acc);
  }
  agg[(size_t)i * HD + d] = acc;
}

// ---------------- fused fc2 -> fc2 -> softmax ----------------
// block = 128 threads, 8 rows per block; h2 kept in LDS, softmax in-block.
__global__ __launch_bounds__(128) void fc2x2_softmax_kernel(const float* __restrict__ agg,
                                                            const float* __restrict__ W2,
                                                            const float* __restrict__ b2,
                                                            float* __restrict__ out) {
  __shared__ float tile[8][HD];
  __shared__ float redm[8][2];
  __shared__ float reds[8][2];
  const int col = threadIdx.x;
  const int row0 = blockIdx.x * 8;
  const int lane = col & 63;
  const int wid = col >> 6;

  // load 8 rows of agg (1024 floats) coalesced
  const float4* src = (const float4*)(agg + (size_t)row0 * HD);
  float4* dst = (float4*)(&tile[0][0]);
  dst[col] = src[col];
  dst[col + 128] = src[col + 128];
  __syncthreads();

  const float bb = b2[col];
  float acc[8];

  // stage 1: h2 = agg @ W2 + b2
#pragma unroll
  for (int r = 0; r < 8; ++r) acc[r] = bb;
  for (int k = 0; k < HD; k += 4) {
    const float w0 = W2[(k + 0) * HD + col];
    const float w1 = W2[(k + 1) * HD + col];
    const float w2w = W2[(k + 2) * HD + col];
    const float w3 = W2[(k + 3) * HD + col];
#pragma unroll
    for (int r = 0; r < 8; ++r) {
      float4 xv = *(const float4*)&tile[r][k];
      acc[r] = fmaf(xv.x, w0, acc[r]);
      acc[r] = fmaf(xv.y, w1, acc[r]);
      acc[r] = fmaf(xv.z, w2w, acc[r]);
      acc[r] = fmaf(xv.w, w3, acc[r]);
    }
  }
  __syncthreads();
#pragma unroll
  for (int r = 0; r < 8; ++r) tile[r][col] = acc[r];
  __syncthreads();

  // stage 2: logits = h2 @ W2 + b2
#pragma unroll
  for (int r = 0; r < 8; ++r) acc[r] = bb;
  for (int k = 0; k < HD; k += 4) {
    const float w0 = W2[(k + 0) * HD + col];
    const float w1 = W2[(k + 1) * HD + col];
    const float w2w = W2[(k + 2) * HD + col];
    const float w3 = W2[(k + 3) * HD + col];
#pragma unroll
    for (int r = 0; r < 8; ++r) {
      float4 xv = *(const float4*)&tile[r][k];
      acc[r] = fmaf(xv.x, w0, acc[r]);
      acc[r] = fmaf(xv.y, w1, acc[r]);
      acc[r] = fmaf(xv.z, w2w, acc[r]);
      acc[r] = fmaf(xv.w, w3, acc[r]);
    }
  }

  // softmax per row across the 128 threads (2 waves)
  float m[8];
#pragma unroll
  for (int r = 0; r < 8; ++r) {
    float mm = acc[r];
#pragma unroll
    for (int off = 1; off < 64; off <<= 1) mm = fmaxf(mm, __shfl_xor(mm, off));
    if (lane == 0) redm[r][wid] = mm;
    m[r] = mm;
  }
  __syncthreads();
#pragma unroll
  for (int r = 0; r < 8; ++r) m[r] = fmaxf(redm[r][0], redm[r][1]);

  float p[8];
#pragma unroll
  for (int r = 0; r < 8; ++r) {
    p[r] = __expf(acc[r] - m[r]);
    float ss = p[r];
#pragma unroll
    for (int off = 1; off < 64; off <<= 1) ss += __shfl_xor(ss, off);
    if (lane == 0) reds[r][wid] = ss;
  }
  __syncthreads();
#pragma unroll
  for (int r = 0; r < 8; ++r) {
    float total = reds[r][0] + reds[r][1];
    out[(size_t)(row0 + r) * HD + col] = p[r] / total;
  }
}

// ---------------- launch ----------------
extern "C" void kernel_launch(void* const* d_in, const int* in_sizes, int n_in,
                              void* d_out, int out_size, void* d_ws, size_t ws_size,
                              hipStream_t stream) {
  (void)in_sizes; (void)n_in; (void)out_size; (void)ws_size;
  const float* x   = (const float*)d_in[0];
  const float* W1  = (const float*)d_in[1];
  const float* b1  = (const float*)d_in[2];
  const float* W2  = (const float*)d_in[3];
  const float* b2  = (const float*)d_in[4];
  const float* adj_vals = (const float*)d_in[5];
  const int* adj_rows   = (const int*)d_in[6];
  const int* adj_cols   = (const int*)d_in[7];
  float* out = (float*)d_out;

  // workspace layout (all 16B-aligned)
  float* h      = (float*)d_ws;            // 6,400,000 floats
  float* agg    = h + (size_t)NN * HD;     // 6,400,000 floats
  int* row_ptr  = (int*)(agg + (size_t)NN * HD);  // 50001 ints
  int* cursor   = row_ptr + 50016;
  int* counts   = cursor + 50016;
  float* vals_s = (float*)(counts + 50016);       // 800,000 floats
  int* cols_s   = (int*)(vals_s + EE);            // 800,000 ints

  hipMemsetAsync(counts, 0, NN * sizeof(int), stream);

  fc1_kernel<<<NN / 16, 128, 0, stream>>>(x, W1, b1, h);
  hist_kernel<<<(EE + 255) / 256, 256, 0, stream>>>(adj_rows, counts);
  scan_kernel<<<1, 1024, 0, stream>>>(counts, row_ptr, cursor);
  permute_kernel<<<(EE + 255) / 256, 256, 0, stream>>>(adj_rows, adj_cols, adj_vals,
                                                       cursor, vals_s, cols_s);
  spmm_kernel<<<NN, 128, 0, stream>>>(h, vals_s, cols_s, row_ptr, agg);
  fc2x2_softmax_kernel<<<NN / 8, 128, 0, stream>>>(agg, W2, b2, out);
}